// Round 7
// baseline (300.604 us; speedup 1.0000x reference)
//
#include <hip/hip_runtime.h>
#include <hip/hip_bf16.h>

#define NSEQ 256
#define DIM 64
#define NB 128
#define NPAIR 384
#define FINF 1e8f
#define LOG2E 1.4426950408889634f
#define LN2 0.6931471805599453f

using f32x4 = __attribute__((ext_vector_type(4))) float;
using s16x8 = __attribute__((ext_vector_type(8))) short;

__device__ __forceinline__ unsigned short bf16u(float f) {
    __hip_bfloat16 h = __float2bfloat16(f);
    return __builtin_bit_cast(unsigned short, h);
}
__device__ __forceinline__ short bf16s(float f) {
    __hip_bfloat16 h = __float2bfloat16(f);
    return __builtin_bit_cast(short, h);
}

// ---------------------------------------------------------------------------
// Kernel 1: D[p][i][j] = |a_i - b_j|^2, stored DIAGONAL-MAJOR:
//   S[p][(i+j) & 255][i]  (diagonals d and d+256 pack one 256-row exactly).
// (unchanged — verified passing)
// ---------------------------------------------------------------------------
__global__ __launch_bounds__(256, 2)
void dist_kernel(const float* __restrict__ X, const float* __restrict__ Y,
                 unsigned short* __restrict__ S) {
    __shared__ __align__(16) short a_lds[NSEQ * DIM];
    __shared__ __align__(16) short b_lds[NSEQ * DIM];  // reused as sbuf later
    __shared__ float a2[NSEQ];
    __shared__ float b2[NSEQ];
    unsigned short* sbuf = reinterpret_cast<unsigned short*>(b_lds);

    const int p = blockIdx.x;
    const int b = p & (NB - 1);
    const int g = p >> 7;  // 0: (x,y)  1: (x,x)  2: (y,y)
    const float* Arow = (g == 2 ? Y : X) + (size_t)b * NSEQ * DIM;
    const float* Brow = (g == 1 ? X : Y) + (size_t)b * NSEQ * DIM;

    const int t = threadIdx.x;
    {
        const float4* av = reinterpret_cast<const float4*>(Arow) + t * (DIM / 4);
        const float4* bv = reinterpret_cast<const float4*>(Brow) + t * (DIM / 4);
        float sa = 0.f, sb = 0.f;
#pragma unroll
        for (int q = 0; q < 8; ++q) {
            float4 a0 = av[2 * q], a1 = av[2 * q + 1];
            float4 b0 = bv[2 * q], b1 = bv[2 * q + 1];
            sa += a0.x * a0.x + a0.y * a0.y + a0.z * a0.z + a0.w * a0.w
                + a1.x * a1.x + a1.y * a1.y + a1.z * a1.z + a1.w * a1.w;
            sb += b0.x * b0.x + b0.y * b0.y + b0.z * b0.z + b0.w * b0.w
                + b1.x * b1.x + b1.y * b1.y + b1.z * b1.z + b1.w * b1.w;
            s16x8 pa = { bf16s(a0.x), bf16s(a0.y), bf16s(a0.z), bf16s(a0.w),
                         bf16s(a1.x), bf16s(a1.y), bf16s(a1.z), bf16s(a1.w) };
            s16x8 pb = { bf16s(b0.x), bf16s(b0.y), bf16s(b0.z), bf16s(b0.w),
                         bf16s(b1.x), bf16s(b1.y), bf16s(b1.z), bf16s(b1.w) };
            const int off = t * DIM + ((q ^ (t & 7)) << 3);
            *reinterpret_cast<s16x8*>(&a_lds[off]) = pa;
            *reinterpret_cast<s16x8*>(&b_lds[off]) = pb;
        }
        a2[t] = sa;
        b2[t] = sb;
    }
    __syncthreads();

    const int wave = t >> 6;
    const int lane = t & 63;
    const int lrow = lane & 15;
    const int lk   = lane >> 4;

    s16x8 bfr[4][2];
    float bn[4];
#pragma unroll
    for (int ct = 0; ct < 4; ++ct) {
        const int c = 64 * wave + ct * 16 + lrow;
#pragma unroll
        for (int kk = 0; kk < 2; ++kk) {
            const int kb = kk * 4 + lk;
            bfr[ct][kk] = *reinterpret_cast<const s16x8*>(
                &b_lds[c * DIM + ((kb ^ (c & 7)) << 3)]);
        }
        bn[ct] = b2[c];
    }
    __syncthreads();  // all waves done with b_lds; it becomes sbuf now

    const size_t pbase = (size_t)p * (NSEQ * NSEQ);
#pragma unroll 1
    for (int stripe = 0; stripe < 4; ++stripe) {
        const int r0 = stripe * 64;
        s16x8 afr[4][2];
#pragma unroll
        for (int rt = 0; rt < 4; ++rt) {
            const int r = r0 + rt * 16 + lrow;
#pragma unroll
            for (int kk = 0; kk < 2; ++kk) {
                const int kb = kk * 4 + lk;
                afr[rt][kk] = *reinterpret_cast<const s16x8*>(
                    &a_lds[r * DIM + ((kb ^ (r & 7)) << 3)]);
            }
        }
#pragma unroll
        for (int ct = 0; ct < 4; ++ct) {
            const int c = 64 * wave + ct * 16 + lrow;
#pragma unroll
            for (int rt = 0; rt < 4; ++rt) {
                f32x4 acc = {0.f, 0.f, 0.f, 0.f};
                acc = __builtin_amdgcn_mfma_f32_16x16x32_bf16(afr[rt][0], bfr[ct][0], acc, 0, 0, 0);
                acc = __builtin_amdgcn_mfma_f32_16x16x32_bf16(afr[rt][1], bfr[ct][1], acc, 0, 0, 0);
#pragma unroll
                for (int jv = 0; jv < 4; ++jv) {
                    const int rloc = rt * 16 + lk * 4 + jv;
                    const float dist = a2[r0 + rloc] + bn[ct] - 2.f * acc[jv];
                    sbuf[rloc * NSEQ + (c ^ (((rloc >> 2) & 3) << 4))] = bf16u(dist);
                }
            }
        }
        __syncthreads();
        const int sl = lane >> 4;
        const int q  = lane & 15;
#pragma unroll
        for (int gg = 0; gg < 16; ++gg) {
            const int s = 64 * wave + gg * 4 + sl;
            const int il0 = 4 * q;
            const int swz = ((q & 3) << 4);
            const int j0 = (s - (r0 + il0 + 0)) & 255;
            const int j1 = (s - (r0 + il0 + 1)) & 255;
            const int j2 = (s - (r0 + il0 + 2)) & 255;
            const int j3 = (s - (r0 + il0 + 3)) & 255;
            unsigned int e0 = sbuf[(il0 + 0) * NSEQ + (j0 ^ swz)];
            unsigned int e1 = sbuf[(il0 + 1) * NSEQ + (j1 ^ swz)];
            unsigned int e2 = sbuf[(il0 + 2) * NSEQ + (j2 ^ swz)];
            unsigned int e3 = sbuf[(il0 + 3) * NSEQ + (j3 ^ swz)];
            uint2 w;
            w.x = e0 | (e1 << 16);
            w.y = e2 | (e3 << 16);
            *reinterpret_cast<uint2*>(&S[pbase + (size_t)s * NSEQ + r0 + 4 * q]) = w;
        }
        __syncthreads();
    }
}

// ---------------------------------------------------------------------------
// Kernel 2: soft-DTW DP, log-domain (round-6 math, verified absmax 0.0),
// now FOUR independent pairs interleaved per wave for ILP: only ~1 wave/SIMD
// is possible (384 DPs, 1024 SIMDs), so dependency stalls must be hidden by
// instruction-level interleave of 4 chains. 96 blocks x 64 threads; 4 LDS
// rings (64 KB); counted vmcnt(32) = 2 chunk-groups in flight.
// ---------------------------------------------------------------------------
__global__ __launch_bounds__(64, 1)
void dtw_kernel(const unsigned short* __restrict__ S, float* __restrict__ rout) {
    __shared__ __align__(16) unsigned short sd[4 * 32 * NSEQ];  // 64 KB
    const int q = blockIdx.x;  // 0..95: pairs 4q..4q+3
    const int L = threadIdx.x;
    const int i0 = 4 * L;

    const unsigned short* Sp[4];
#pragma unroll
    for (int pp = 0; pp < 4; ++pp)
        Sp[pp] = S + (size_t)(4 * q + pp) * (NSEQ * NSEQ);

    auto stage = [&](int pp, int cc) {  // rows (8cc..8cc+7)&255 -> slot cc&3
        const int row = (8 * cc) & 255;
        const unsigned short* gsrc = Sp[pp] + row * NSEQ + L * 8;
        unsigned short* lbase = &sd[pp * 8192 + (cc & 3) * 2048];
#pragma unroll
        for (int i = 0; i < 4; ++i) {
            __builtin_amdgcn_global_load_lds(
                (const __attribute__((address_space(1))) void*)(gsrc + i * 512),
                (__attribute__((address_space(3))) void*)(lbase + i * 512),
                16, 0, 0);
        }
    };

    float r1[4][4], r2[4][4], up1[4], up2[4];
#pragma unroll
    for (int pp = 0; pp < 4; ++pp) {
#pragma unroll
        for (int k = 0; k < 4; ++k) { r1[pp][k] = FINF; r2[pp][k] = FINF; }
        up1[pp] = FINF;                   // shift(r1[3])
        up2[pp] = (L == 0) ? 0.f : FINF;  // shift(r2[3]); lane0: R[-1][-1]=0
    }

    const int finf_bits = __builtin_bit_cast(int, FINF);

    auto step = [&](int pp, int d) {
        const uint2 w = *reinterpret_cast<const uint2*>(
            &sd[pp * 8192 + ((d & 31) << 8) + i0]);
        float dv[4];
        dv[0] = __builtin_bit_cast(float, w.x << 16);
        dv[1] = __builtin_bit_cast(float, w.x & 0xffff0000u);
        dv[2] = __builtin_bit_cast(float, w.y << 16);
        dv[3] = __builtin_bit_cast(float, w.y & 0xffff0000u);
        float rn[4];
#pragma unroll
        for (int k = 0; k < 4; ++k) {
            const float a = (k == 0) ? up2[pp] : r2[pp][k - 1];   // R'[i-1][j-1]
            const float bb = (k == 0) ? up1[pp] : r1[pp][k - 1];  // R'[i-1][j]
            const float c = r1[pp][k];                             // R'[i][j-1]
            const float m   = fminf(fminf(a, bb), c);
            const float med = __builtin_amdgcn_fmed3f(a, bb, c);
            const float M   = fmaxf(fmaxf(a, bb), c);
            const float e = 1.0f + __builtin_amdgcn_exp2f(m - med)
                                 + __builtin_amdgcn_exp2f(m - M);
            const float sm = m - __builtin_amdgcn_logf(e);  // v_log_f32 = log2
            rn[k] = __builtin_fmaf(dv[k], LOG2E, sm);
        }
        // boundary: lane L gets lane L-1's rn[3]; lane 0 keeps old = FINF
        const float up1n = __builtin_bit_cast(float,
            __builtin_amdgcn_update_dpp(finf_bits,
                __builtin_bit_cast(int, rn[3]),
                0x138 /*wave_shr:1*/, 0xF, 0xF, false));
        up2[pp] = up1[pp];
        up1[pp] = up1n;
#pragma unroll
        for (int k = 0; k < 4; ++k) { r2[pp][k] = r1[pp][k]; r1[pp][k] = rn[k]; }
    };

    // prologue: chunks 0..2 for all pairs (48 loads); chunk 0 landed at <=32
#pragma unroll
    for (int cc = 0; cc < 3; ++cc)
#pragma unroll
        for (int pp = 0; pp < 4; ++pp) stage(pp, cc);
    asm volatile("s_waitcnt vmcnt(32)" ::: "memory");

#pragma unroll 1
    for (int c = 0; c < 63; ++c) {
#pragma unroll
        for (int pp = 0; pp < 4; ++pp) stage(pp, c + 3);  // c>=61 wraps, harmless
        asm volatile("s_waitcnt vmcnt(32)" ::: "memory");  // chunk c+1 landed
        const int d0 = 8 * c;
#pragma unroll
        for (int u = 0; u < 8; ++u)
#pragma unroll
            for (int pp = 0; pp < 4; ++pp) step(pp, d0 + u);
    }
    // tail: steps 504..510 (chunk 63 landed: last 32 outstanding = 64,65)
#pragma unroll
    for (int u = 0; u < 7; ++u)
#pragma unroll
        for (int pp = 0; pp < 4; ++pp) step(pp, 504 + u);

    if (L == 63) {
#pragma unroll
        for (int pp = 0; pp < 4; ++pp)
            rout[4 * q + pp] = r1[pp][3] * LN2;  // base-2 -> nats
    }
}

// ---------------------------------------------------------------------------
// Kernel 3: loss = mean_b( r[b] - 0.5*(r[b+128] + r[b+256]) ) + 1e-5
// ---------------------------------------------------------------------------
__global__ void reduce_kernel(const float* __restrict__ rr, float* __restrict__ out) {
    const int t = threadIdx.x;  // 128 threads
    float v = rr[t] - 0.5f * (rr[t + 128] + rr[t + 256]);
#pragma unroll
    for (int o = 32; o > 0; o >>= 1) v += __shfl_down(v, o);
    __shared__ float sred[2];
    if ((t & 63) == 0) sred[t >> 6] = v;
    __syncthreads();
    if (t == 0) out[0] = (sred[0] + sred[1]) * (1.f / 128.f) + 1e-5f;
}

extern "C" void kernel_launch(void* const* d_in, const int* in_sizes, int n_in,
                              void* d_out, int out_size, void* d_ws, size_t ws_size,
                              hipStream_t stream) {
    const float* X = (const float*)d_in[0];  // outputs (128,256,64) f32
    const float* Y = (const float*)d_in[1];  // targets (128,256,64) f32
    float* out = (float*)d_out;

    const size_t dbytes = (size_t)NPAIR * NSEQ * NSEQ * sizeof(unsigned short);
    const size_t need = dbytes + (size_t)NPAIR * sizeof(float);
    if (ws_size < need) {
        hipMemsetAsync(d_out, 0x7f, sizeof(float), stream);  // sentinel
        return;
    }
    unsigned short* Sws = (unsigned short*)d_ws;
    float* rws = (float*)((char*)d_ws + dbytes);

    dist_kernel<<<NPAIR, 256, 0, stream>>>(X, Y, Sws);
    dtw_kernel<<<NPAIR / 4, 64, 0, stream>>>(Sws, rws);
    reduce_kernel<<<1, 128, 0, stream>>>(rws, out);
}

// Round 8
// 115.349 us; speedup vs baseline: 2.6060x; 2.6060x over previous
//
#include <hip/hip_runtime.h>
#include <hip/hip_bf16.h>

#define NSEQ 256
#define DIM 64
#define NB 128
#define NPAIR 384
#define FINF 1e8f
#define LOG2E 1.4426950408889634f
#define LN2 0.6931471805599453f

using f32x4 = __attribute__((ext_vector_type(4))) float;
using s16x8 = __attribute__((ext_vector_type(8))) short;

__device__ __forceinline__ unsigned short bf16u(float f) {
    __hip_bfloat16 h = __float2bfloat16(f);
    return __builtin_bit_cast(unsigned short, h);
}
__device__ __forceinline__ short bf16s(float f) {
    __hip_bfloat16 h = __float2bfloat16(f);
    return __builtin_bit_cast(short, h);
}

// ---------------------------------------------------------------------------
// Kernel 1: D[p][i][j] = |a_i - b_j|^2, stored DIAGONAL-MAJOR:
//   S[p][(i+j) & 255][i]  (diagonals d and d+256 pack one 256-row exactly).
// (unchanged — verified passing)
// ---------------------------------------------------------------------------
__global__ __launch_bounds__(256, 2)
void dist_kernel(const float* __restrict__ X, const float* __restrict__ Y,
                 unsigned short* __restrict__ S) {
    __shared__ __align__(16) short a_lds[NSEQ * DIM];
    __shared__ __align__(16) short b_lds[NSEQ * DIM];  // reused as sbuf later
    __shared__ float a2[NSEQ];
    __shared__ float b2[NSEQ];
    unsigned short* sbuf = reinterpret_cast<unsigned short*>(b_lds);

    const int p = blockIdx.x;
    const int b = p & (NB - 1);
    const int g = p >> 7;  // 0: (x,y)  1: (x,x)  2: (y,y)
    const float* Arow = (g == 2 ? Y : X) + (size_t)b * NSEQ * DIM;
    const float* Brow = (g == 1 ? X : Y) + (size_t)b * NSEQ * DIM;

    const int t = threadIdx.x;
    {
        const float4* av = reinterpret_cast<const float4*>(Arow) + t * (DIM / 4);
        const float4* bv = reinterpret_cast<const float4*>(Brow) + t * (DIM / 4);
        float sa = 0.f, sb = 0.f;
#pragma unroll
        for (int q = 0; q < 8; ++q) {
            float4 a0 = av[2 * q], a1 = av[2 * q + 1];
            float4 b0 = bv[2 * q], b1 = bv[2 * q + 1];
            sa += a0.x * a0.x + a0.y * a0.y + a0.z * a0.z + a0.w * a0.w
                + a1.x * a1.x + a1.y * a1.y + a1.z * a1.z + a1.w * a1.w;
            sb += b0.x * b0.x + b0.y * b0.y + b0.z * b0.z + b0.w * b0.w
                + b1.x * b1.x + b1.y * b1.y + b1.z * b1.z + b1.w * b1.w;
            s16x8 pa = { bf16s(a0.x), bf16s(a0.y), bf16s(a0.z), bf16s(a0.w),
                         bf16s(a1.x), bf16s(a1.y), bf16s(a1.z), bf16s(a1.w) };
            s16x8 pb = { bf16s(b0.x), bf16s(b0.y), bf16s(b0.z), bf16s(b0.w),
                         bf16s(b1.x), bf16s(b1.y), bf16s(b1.z), bf16s(b1.w) };
            const int off = t * DIM + ((q ^ (t & 7)) << 3);
            *reinterpret_cast<s16x8*>(&a_lds[off]) = pa;
            *reinterpret_cast<s16x8*>(&b_lds[off]) = pb;
        }
        a2[t] = sa;
        b2[t] = sb;
    }
    __syncthreads();

    const int wave = t >> 6;
    const int lane = t & 63;
    const int lrow = lane & 15;
    const int lk   = lane >> 4;

    s16x8 bfr[4][2];
    float bn[4];
#pragma unroll
    for (int ct = 0; ct < 4; ++ct) {
        const int c = 64 * wave + ct * 16 + lrow;
#pragma unroll
        for (int kk = 0; kk < 2; ++kk) {
            const int kb = kk * 4 + lk;
            bfr[ct][kk] = *reinterpret_cast<const s16x8*>(
                &b_lds[c * DIM + ((kb ^ (c & 7)) << 3)]);
        }
        bn[ct] = b2[c];
    }
    __syncthreads();  // all waves done with b_lds; it becomes sbuf now

    const size_t pbase = (size_t)p * (NSEQ * NSEQ);
#pragma unroll 1
    for (int stripe = 0; stripe < 4; ++stripe) {
        const int r0 = stripe * 64;
        s16x8 afr[4][2];
#pragma unroll
        for (int rt = 0; rt < 4; ++rt) {
            const int r = r0 + rt * 16 + lrow;
#pragma unroll
            for (int kk = 0; kk < 2; ++kk) {
                const int kb = kk * 4 + lk;
                afr[rt][kk] = *reinterpret_cast<const s16x8*>(
                    &a_lds[r * DIM + ((kb ^ (r & 7)) << 3)]);
            }
        }
#pragma unroll
        for (int ct = 0; ct < 4; ++ct) {
            const int c = 64 * wave + ct * 16 + lrow;
#pragma unroll
            for (int rt = 0; rt < 4; ++rt) {
                f32x4 acc = {0.f, 0.f, 0.f, 0.f};
                acc = __builtin_amdgcn_mfma_f32_16x16x32_bf16(afr[rt][0], bfr[ct][0], acc, 0, 0, 0);
                acc = __builtin_amdgcn_mfma_f32_16x16x32_bf16(afr[rt][1], bfr[ct][1], acc, 0, 0, 0);
#pragma unroll
                for (int jv = 0; jv < 4; ++jv) {
                    const int rloc = rt * 16 + lk * 4 + jv;
                    const float dist = a2[r0 + rloc] + bn[ct] - 2.f * acc[jv];
                    sbuf[rloc * NSEQ + (c ^ (((rloc >> 2) & 3) << 4))] = bf16u(dist);
                }
            }
        }
        __syncthreads();
        const int sl = lane >> 4;
        const int q  = lane & 15;
#pragma unroll
        for (int gg = 0; gg < 16; ++gg) {
            const int s = 64 * wave + gg * 4 + sl;
            const int il0 = 4 * q;
            const int swz = ((q & 3) << 4);
            const int j0 = (s - (r0 + il0 + 0)) & 255;
            const int j1 = (s - (r0 + il0 + 1)) & 255;
            const int j2 = (s - (r0 + il0 + 2)) & 255;
            const int j3 = (s - (r0 + il0 + 3)) & 255;
            unsigned int e0 = sbuf[(il0 + 0) * NSEQ + (j0 ^ swz)];
            unsigned int e1 = sbuf[(il0 + 1) * NSEQ + (j1 ^ swz)];
            unsigned int e2 = sbuf[(il0 + 2) * NSEQ + (j2 ^ swz)];
            unsigned int e3 = sbuf[(il0 + 3) * NSEQ + (j3 ^ swz)];
            uint2 w;
            w.x = e0 | (e1 << 16);
            w.y = e2 | (e3 << 16);
            *reinterpret_cast<uint2*>(&S[pbase + (size_t)s * NSEQ + r0 + 4 * q]) = w;
        }
        __syncthreads();
    }
}

// ---------------------------------------------------------------------------
// Kernel 2: soft-DTW DP, log-domain (round-6 math, verified absmax 0.0),
// one pair/wave, 384 blocks. NEW: chunk-level register double-buffer of D —
// the 8 steps of chunk c run on wvA (pure register math, no memory ops)
// while the 8 ds_read_b64 for chunk c+1 fill wvB; swap. LDS ring staged via
// global_load_lds (4 slots x 8 diagonals, counted vmcnt).
// ---------------------------------------------------------------------------
__global__ __launch_bounds__(64, 1)
void dtw_kernel(const unsigned short* __restrict__ S, float* __restrict__ rout) {
    __shared__ __align__(16) unsigned short sd[32 * NSEQ];  // 16 KB ring
    const int p = blockIdx.x;
    const int L = threadIdx.x;
    const unsigned short* Sp = S + (size_t)p * (NSEQ * NSEQ);
    const int i0 = 4 * L;

    auto stage = [&](int cc) {  // rows (8cc..8cc+7)&255 -> slot cc&3
        const int row = (8 * cc) & 255;
        const unsigned short* gsrc = Sp + row * NSEQ + L * 8;
        unsigned short* lbase = &sd[(cc & 3) * 2048];
#pragma unroll
        for (int i = 0; i < 4; ++i) {
            __builtin_amdgcn_global_load_lds(
                (const __attribute__((address_space(1))) void*)(gsrc + i * 512),
                (__attribute__((address_space(3))) void*)(lbase + i * 512),
                16, 0, 0);
        }
    };

    auto ldchunk = [&](uint2* wv, int cc) {  // LDS slot -> 8x uint2 regs
        const unsigned short* base = &sd[(cc & 3) * 2048 + i0];
#pragma unroll
        for (int u = 0; u < 8; ++u)
            wv[u] = *reinterpret_cast<const uint2*>(base + u * 256);
        __builtin_amdgcn_sched_barrier(0);  // pin: reads issue here, early
    };

    float r1[4], r2[4];
#pragma unroll
    for (int k = 0; k < 4; ++k) { r1[k] = FINF; r2[k] = FINF; }
    float up1 = FINF;                   // shift(r1[3]) for current step
    float up2 = (L == 0) ? 0.f : FINF;  // shift(r2[3]); lane0 row0: R[-1][-1]=0

    const int finf_bits = __builtin_bit_cast(int, FINF);

    auto step = [&](uint2 w) {
        float dv[4];
        dv[0] = __builtin_bit_cast(float, w.x << 16);
        dv[1] = __builtin_bit_cast(float, w.x & 0xffff0000u);
        dv[2] = __builtin_bit_cast(float, w.y << 16);
        dv[3] = __builtin_bit_cast(float, w.y & 0xffff0000u);
        float rn[4];
#pragma unroll
        for (int k = 0; k < 4; ++k) {
            const float a = (k == 0) ? up2 : r2[k - 1];   // R'[i-1][j-1]
            const float bb = (k == 0) ? up1 : r1[k - 1];  // R'[i-1][j]
            const float c = r1[k];                         // R'[i][j-1]
            const float m   = fminf(fminf(a, bb), c);
            const float med = __builtin_amdgcn_fmed3f(a, bb, c);
            const float M   = fmaxf(fmaxf(a, bb), c);
            const float e = 1.0f + __builtin_amdgcn_exp2f(m - med)
                                 + __builtin_amdgcn_exp2f(m - M);
            const float sm = m - __builtin_amdgcn_logf(e);  // v_log_f32 = log2
            rn[k] = __builtin_fmaf(dv[k], LOG2E, sm);
        }
        // boundary: lane L gets lane L-1's rn[3]; lane 0 keeps old = FINF
        const float up1n = __builtin_bit_cast(float,
            __builtin_amdgcn_update_dpp(finf_bits,
                __builtin_bit_cast(int, rn[3]),
                0x138 /*wave_shr:1*/, 0xF, 0xF, false));
        up2 = up1;
        up1 = up1n;
#pragma unroll
        for (int k = 0; k < 4; ++k) { r2[k] = r1[k]; r1[k] = rn[k]; }
    };

    uint2 wvA[8], wvB[8];

    stage(0); stage(1); stage(2);
    asm volatile("s_waitcnt vmcnt(8)" ::: "memory");  // chunk 0 landed
    ldchunk(wvA, 0);

#pragma unroll 1
    for (int cit = 0; cit < 31; ++cit) {  // chunks c, c+1 per iteration
        const int c = 2 * cit;
        stage(c + 3);
        asm volatile("s_waitcnt vmcnt(8)" ::: "memory");  // chunk c+1 landed
        ldchunk(wvB, c + 1);
#pragma unroll
        for (int u = 0; u < 8; ++u) step(wvA[u]);         // steps of chunk c
        stage(c + 4);
        asm volatile("s_waitcnt vmcnt(8)" ::: "memory");  // chunk c+2 landed
        ldchunk(wvA, c + 2);
#pragma unroll
        for (int u = 0; u < 8; ++u) step(wvB[u]);         // steps of chunk c+1
    }
    // chunks 0..61 stepped; wvA holds chunk 62; staged through chunk 64 (wrap)
#pragma unroll
    for (int u = 0; u < 8; ++u) step(wvA[u]);             // steps 496..503
    asm volatile("s_waitcnt vmcnt(4)" ::: "memory");      // chunk 63 landed
    ldchunk(wvB, 63);                                     // slot 3 (64 wrote 0)
#pragma unroll
    for (int u = 0; u < 7; ++u) step(wvB[u]);             // steps 504..510
    asm volatile("s_waitcnt vmcnt(0)" ::: "memory");      // drain wrapped stage

    if (L == 63) rout[p] = r1[3] * LN2;  // base-2 -> nats
}

// ---------------------------------------------------------------------------
// Kernel 3: loss = mean_b( r[b] - 0.5*(r[b+128] + r[b+256]) ) + 1e-5
// ---------------------------------------------------------------------------
__global__ void reduce_kernel(const float* __restrict__ rr, float* __restrict__ out) {
    const int t = threadIdx.x;  // 128 threads
    float v = rr[t] - 0.5f * (rr[t + 128] + rr[t + 256]);
#pragma unroll
    for (int o = 32; o > 0; o >>= 1) v += __shfl_down(v, o);
    __shared__ float sred[2];
    if ((t & 63) == 0) sred[t >> 6] = v;
    __syncthreads();
    if (t == 0) out[0] = (sred[0] + sred[1]) * (1.f / 128.f) + 1e-5f;
}

extern "C" void kernel_launch(void* const* d_in, const int* in_sizes, int n_in,
                              void* d_out, int out_size, void* d_ws, size_t ws_size,
                              hipStream_t stream) {
    const float* X = (const float*)d_in[0];  // outputs (128,256,64) f32
    const float* Y = (const float*)d_in[1];  // targets (128,256,64) f32
    float* out = (float*)d_out;

    const size_t dbytes = (size_t)NPAIR * NSEQ * NSEQ * sizeof(unsigned short);
    const size_t need = dbytes + (size_t)NPAIR * sizeof(float);
    if (ws_size < need) {
        hipMemsetAsync(d_out, 0x7f, sizeof(float), stream);  // sentinel
        return;
    }
    unsigned short* Sws = (unsigned short*)d_ws;
    float* rws = (float*)((char*)d_ws + dbytes);

    dist_kernel<<<NPAIR, 256, 0, stream>>>(X, Y, Sws);
    dtw_kernel<<<NPAIR, 64, 0, stream>>>(Sws, rws);
    reduce_kernel<<<1, 128, 0, stream>>>(rws, out);
}

// Round 9
// 108.200 us; speedup vs baseline: 2.7782x; 1.0661x over previous
//
#include <hip/hip_runtime.h>
#include <hip/hip_bf16.h>

#define NSEQ 256
#define DIM 64
#define NB 128
#define NPAIR 384
#define FINF 1e8f
#define LOG2E 1.4426950408889634f
#define LN2 0.6931471805599453f

using f32x4 = __attribute__((ext_vector_type(4))) float;
using s16x8 = __attribute__((ext_vector_type(8))) short;
using u32x2 = __attribute__((ext_vector_type(2))) unsigned;

__device__ __forceinline__ unsigned short bf16u(float f) {
    __hip_bfloat16 h = __float2bfloat16(f);
    return __builtin_bit_cast(unsigned short, h);
}
__device__ __forceinline__ short bf16s(float f) {
    __hip_bfloat16 h = __float2bfloat16(f);
    return __builtin_bit_cast(short, h);
}
__device__ __forceinline__ float min3f(float a, float b, float c) {
    float d; asm("v_min3_f32 %0, %1, %2, %3" : "=v"(d) : "v"(a), "v"(b), "v"(c));
    return d;
}
__device__ __forceinline__ float max3f(float a, float b, float c) {
    float d; asm("v_max3_f32 %0, %1, %2, %3" : "=v"(d) : "v"(a), "v"(b), "v"(c));
    return d;
}

// ---------------------------------------------------------------------------
// Kernel 1: D[p][i][j] = |a_i - b_j|^2, stored DIAGONAL-MAJOR:
//   S[p][(i+j) & 255][i]. NOW 2 blocks per pair (768 blocks, 128 rows each,
//   ~50 KB LDS -> 3 blocks/CU -> exactly one dispatch round).
// ---------------------------------------------------------------------------
__global__ __launch_bounds__(256, 3)
void dist_kernel(const float* __restrict__ X, const float* __restrict__ Y,
                 unsigned short* __restrict__ S) {
    __shared__ __align__(16) short b_lds[NSEQ * DIM];   // 32 KB; reused as sbuf
    __shared__ __align__(16) short a_lds[128 * DIM];    // 16 KB (this half's A)
    __shared__ float a2[128];
    __shared__ float b2[NSEQ];
    unsigned short* sbuf = reinterpret_cast<unsigned short*>(b_lds);

    const int bid = blockIdx.x;
    const int p = bid >> 1;       // pair 0..383
    const int h = bid & 1;        // row-half 0..1
    const int b = p & (NB - 1);
    const int g = p >> 7;         // 0: (x,y)  1: (x,x)  2: (y,y)
    const float* Arow = (g == 2 ? Y : X) + (size_t)b * NSEQ * DIM
                        + (size_t)h * 128 * DIM;
    const float* Brow = (g == 1 ? X : Y) + (size_t)b * NSEQ * DIM;

    const int t = threadIdx.x;
    // stage B row t (all 256 threads)
    {
        const float4* bv = reinterpret_cast<const float4*>(Brow) + t * (DIM / 4);
        float sb = 0.f;
#pragma unroll
        for (int q = 0; q < 8; ++q) {
            float4 b0 = bv[2 * q], b1 = bv[2 * q + 1];
            sb += b0.x * b0.x + b0.y * b0.y + b0.z * b0.z + b0.w * b0.w
                + b1.x * b1.x + b1.y * b1.y + b1.z * b1.z + b1.w * b1.w;
            s16x8 pb = { bf16s(b0.x), bf16s(b0.y), bf16s(b0.z), bf16s(b0.w),
                         bf16s(b1.x), bf16s(b1.y), bf16s(b1.z), bf16s(b1.w) };
            *reinterpret_cast<s16x8*>(&b_lds[t * DIM + ((q ^ (t & 7)) << 3)]) = pb;
        }
        b2[t] = sb;
    }
    // stage A row t (threads 0..127, local row index)
    if (t < 128) {
        const float4* av = reinterpret_cast<const float4*>(Arow) + t * (DIM / 4);
        float sa = 0.f;
#pragma unroll
        for (int q = 0; q < 8; ++q) {
            float4 a0 = av[2 * q], a1 = av[2 * q + 1];
            sa += a0.x * a0.x + a0.y * a0.y + a0.z * a0.z + a0.w * a0.w
                + a1.x * a1.x + a1.y * a1.y + a1.z * a1.z + a1.w * a1.w;
            s16x8 pa = { bf16s(a0.x), bf16s(a0.y), bf16s(a0.z), bf16s(a0.w),
                         bf16s(a1.x), bf16s(a1.y), bf16s(a1.z), bf16s(a1.w) };
            *reinterpret_cast<s16x8*>(&a_lds[t * DIM + ((q ^ (t & 7)) << 3)]) = pa;
        }
        a2[t] = sa;
    }
    __syncthreads();

    const int wave = t >> 6;
    const int lane = t & 63;
    const int lrow = lane & 15;
    const int lk   = lane >> 4;

    s16x8 bfr[4][2];
    float bn[4];
#pragma unroll
    for (int ct = 0; ct < 4; ++ct) {
        const int c = 64 * wave + ct * 16 + lrow;
#pragma unroll
        for (int kk = 0; kk < 2; ++kk) {
            const int kb = kk * 4 + lk;
            bfr[ct][kk] = *reinterpret_cast<const s16x8*>(
                &b_lds[c * DIM + ((kb ^ (c & 7)) << 3)]);
        }
        bn[ct] = b2[c];
    }
    __syncthreads();  // all waves done with b_lds; it becomes sbuf now

    const size_t pbase = (size_t)p * (NSEQ * NSEQ);
#pragma unroll 1
    for (int sloc = 0; sloc < 2; ++sloc) {     // two 64-row stripes
        const int rl0 = sloc * 64;             // local stripe base in a_lds
        const int r0  = h * 128 + rl0;         // global stripe base
        s16x8 afr[4][2];
#pragma unroll
        for (int rt = 0; rt < 4; ++rt) {
            const int rl = rl0 + rt * 16 + lrow;  // local row
#pragma unroll
            for (int kk = 0; kk < 2; ++kk) {
                const int kb = kk * 4 + lk;
                afr[rt][kk] = *reinterpret_cast<const s16x8*>(
                    &a_lds[rl * DIM + ((kb ^ (rl & 7)) << 3)]);
            }
        }
#pragma unroll
        for (int ct = 0; ct < 4; ++ct) {
            const int c = 64 * wave + ct * 16 + lrow;
#pragma unroll
            for (int rt = 0; rt < 4; ++rt) {
                f32x4 acc = {0.f, 0.f, 0.f, 0.f};
                acc = __builtin_amdgcn_mfma_f32_16x16x32_bf16(afr[rt][0], bfr[ct][0], acc, 0, 0, 0);
                acc = __builtin_amdgcn_mfma_f32_16x16x32_bf16(afr[rt][1], bfr[ct][1], acc, 0, 0, 0);
#pragma unroll
                for (int jv = 0; jv < 4; ++jv) {
                    const int rloc = rt * 16 + lk * 4 + jv;  // row within stripe
                    const float dist = a2[rl0 + rloc] + bn[ct] - 2.f * acc[jv];
                    sbuf[rloc * NSEQ + (c ^ (((rloc >> 2) & 3) << 4))] = bf16u(dist);
                }
            }
        }
        __syncthreads();
        // writeout: per s-row this stripe contributes S[s][r0..r0+64) (128B)
        const int sl = lane >> 4;
        const int q  = lane & 15;
#pragma unroll
        for (int gg = 0; gg < 16; ++gg) {
            const int s = 64 * wave + gg * 4 + sl;
            const int il0 = 4 * q;
            const int swz = ((q & 3) << 4);
            const int j0 = (s - (r0 + il0 + 0)) & 255;
            const int j1 = (s - (r0 + il0 + 1)) & 255;
            const int j2 = (s - (r0 + il0 + 2)) & 255;
            const int j3 = (s - (r0 + il0 + 3)) & 255;
            unsigned int e0 = sbuf[(il0 + 0) * NSEQ + (j0 ^ swz)];
            unsigned int e1 = sbuf[(il0 + 1) * NSEQ + (j1 ^ swz)];
            unsigned int e2 = sbuf[(il0 + 2) * NSEQ + (j2 ^ swz)];
            unsigned int e3 = sbuf[(il0 + 3) * NSEQ + (j3 ^ swz)];
            uint2 w;
            w.x = e0 | (e1 << 16);
            w.y = e2 | (e3 << 16);
            *reinterpret_cast<uint2*>(&S[pbase + (size_t)s * NSEQ + r0 + 4 * q]) = w;
        }
        __syncthreads();
    }
}

// ---------------------------------------------------------------------------
// Kernel 2: soft-DTW DP, log-domain (round-6 math, verified absmax 0.0).
// Chunk-level register double-buffer now pinned with INLINE-ASM ds_read_b64
// (cannot be folded) + counted lgkmcnt(0)+sched_barrier; diagonal state
// ping-pongs (no copies); min3/max3 single-instruction.
// ---------------------------------------------------------------------------
#define DSR(dst, base, offstr) \
    asm volatile("ds_read_b64 %0, %1 offset:" offstr : "=v"(dst) : "v"(base))
#define DSR8(wv, base) \
    DSR(wv[0], base, "0");    DSR(wv[1], base, "512");  \
    DSR(wv[2], base, "1024"); DSR(wv[3], base, "1536"); \
    DSR(wv[4], base, "2048"); DSR(wv[5], base, "2560"); \
    DSR(wv[6], base, "3072"); DSR(wv[7], base, "3584")
#define LGKM0() do { \
    asm volatile("s_waitcnt lgkmcnt(0)" ::: "memory"); \
    __builtin_amdgcn_sched_barrier(0); } while (0)

__global__ __launch_bounds__(64, 1)
void dtw_kernel(const unsigned short* __restrict__ S, float* __restrict__ rout) {
    __shared__ __align__(16) unsigned short sd[32 * NSEQ];  // 16 KB ring
    const int p = blockIdx.x;
    const int L = threadIdx.x;
    const unsigned short* Sp = S + (size_t)p * (NSEQ * NSEQ);

    auto stage = [&](int cc) {  // rows (8cc..8cc+7)&255 -> slot cc&3
        const int row = (8 * cc) & 255;
        const unsigned short* gsrc = Sp + row * NSEQ + L * 8;
        unsigned short* lbase = &sd[(cc & 3) * 2048];
#pragma unroll
        for (int i = 0; i < 4; ++i) {
            __builtin_amdgcn_global_load_lds(
                (const __attribute__((address_space(1))) void*)(gsrc + i * 512),
                (__attribute__((address_space(3))) void*)(lbase + i * 512),
                16, 0, 0);
        }
    };

    // LDS byte address of sd[0] for this lane's column (i0*2 = 8L bytes)
    const unsigned sd0 = (unsigned)(uintptr_t)
        (__attribute__((address_space(3))) unsigned short*)&sd[0];
    const unsigned lanebyte = sd0 + (L << 3);

    float r1[4], r2[4];
#pragma unroll
    for (int k = 0; k < 4; ++k) { r1[k] = FINF; r2[k] = FINF; }
    float up1 = FINF;                   // shift of newest diag's [3]
    float up2 = (L == 0) ? 0.f : FINF;  // shift of older diag's [3]; R[-1][-1]=0

    const int finf_bits = __builtin_bit_cast(int, FINF);

    // step: N = newest diag (d-1), O = older (d-2); writes result into O
    // (which becomes newest) and new up into upO. Caller alternates args.
    auto step = [&](float (&N)[4], float (&O)[4], float& upN, float& upO,
                    u32x2 w) {
        float dv0 = __builtin_bit_cast(float, w.x << 16);
        float dv1 = __builtin_bit_cast(float, w.x & 0xffff0000u);
        float dv2 = __builtin_bit_cast(float, w.y << 16);
        float dv3 = __builtin_bit_cast(float, w.y & 0xffff0000u);
        float rn[4];
        float aprev = upO, bprev = upN;
#pragma unroll
        for (int k = 0; k < 4; ++k) {
            const float dv = (k == 0) ? dv0 : (k == 1) ? dv1 : (k == 2) ? dv2 : dv3;
            const float a = aprev;   // R'[i-1][j-1]
            const float bb = bprev;  // R'[i-1][j]
            const float c = N[k];    // R'[i][j-1]
            aprev = O[k];            // save before overwrite
            bprev = N[k];
            const float m   = min3f(a, bb, c);
            const float med = __builtin_amdgcn_fmed3f(a, bb, c);
            const float M   = max3f(a, bb, c);
            const float e = 1.0f + __builtin_amdgcn_exp2f(m - med)
                                 + __builtin_amdgcn_exp2f(m - M);
            const float sm = m - __builtin_amdgcn_logf(e);  // v_log_f32 = log2
            rn[k] = __builtin_fmaf(dv, LOG2E, sm);
            O[k] = rn[k];
        }
        upO = __builtin_bit_cast(float,
            __builtin_amdgcn_update_dpp(finf_bits,
                __builtin_bit_cast(int, rn[3]),
                0x138 /*wave_shr:1*/, 0xF, 0xF, false));
    };

    u32x2 wvA[8], wvB[8];

    stage(0); stage(1); stage(2);
    asm volatile("s_waitcnt vmcnt(8)" ::: "memory");  // chunk 0 landed
    {
        const unsigned baseA = lanebyte;  // slot 0
        DSR8(wvA, baseA);
        LGKM0();
    }

#pragma unroll 1
    for (int cit = 0; cit < 31; ++cit) {  // chunks c, c+1 per iteration
        const int c = 2 * cit;
        stage(c + 3);
        asm volatile("s_waitcnt vmcnt(8)" ::: "memory");  // chunk c+1 in LDS
        const unsigned baseB = lanebyte + (((c + 1) & 3) << 12);
        DSR8(wvB, baseB);                 // issue early; steps below hide it
#pragma unroll
        for (int u = 0; u < 4; ++u) {     // 8 steps of chunk c (ping-pong)
            step(r1, r2, up1, up2, wvA[2 * u]);
            step(r2, r1, up2, up1, wvA[2 * u + 1]);
        }
        LGKM0();                          // wvB ready

        stage(c + 4);
        asm volatile("s_waitcnt vmcnt(8)" ::: "memory");  // chunk c+2 in LDS
        const unsigned baseA = lanebyte + (((c + 2) & 3) << 12);
        DSR8(wvA, baseA);
#pragma unroll
        for (int u = 0; u < 4; ++u) {     // 8 steps of chunk c+1
            step(r1, r2, up1, up2, wvB[2 * u]);
            step(r2, r1, up2, up1, wvB[2 * u + 1]);
        }
        LGKM0();                          // wvA ready
    }
    // loop consumed chunks 0..61; wvA holds 62; outstanding stages: 63,64
#pragma unroll
    for (int u = 0; u < 4; ++u) {         // steps 496..503
        step(r1, r2, up1, up2, wvA[2 * u]);
        step(r2, r1, up2, up1, wvA[2 * u + 1]);
    }
    asm volatile("s_waitcnt vmcnt(4)" ::: "memory");  // chunk 63 landed
    {
        const unsigned baseB = lanebyte + (3u << 12);  // slot 63&3 = 3
        DSR8(wvB, baseB);
        LGKM0();
    }
    // steps 504..510: A,B,A,B,A,B,A  -> final newest written into r2
    step(r1, r2, up1, up2, wvB[0]);
    step(r2, r1, up2, up1, wvB[1]);
    step(r1, r2, up1, up2, wvB[2]);
    step(r2, r1, up2, up1, wvB[3]);
    step(r1, r2, up1, up2, wvB[4]);
    step(r2, r1, up2, up1, wvB[5]);
    step(r1, r2, up1, up2, wvB[6]);
    asm volatile("s_waitcnt vmcnt(0)" ::: "memory");  // drain wrapped stage

    if (L == 63) rout[p] = r2[3] * LN2;  // base-2 -> nats
}

// ---------------------------------------------------------------------------
// Kernel 3: loss = mean_b( r[b] - 0.5*(r[b+128] + r[b+256]) ) + 1e-5
// ---------------------------------------------------------------------------
__global__ void reduce_kernel(const float* __restrict__ rr, float* __restrict__ out) {
    const int t = threadIdx.x;  // 128 threads
    float v = rr[t] - 0.5f * (rr[t + 128] + rr[t + 256]);
#pragma unroll
    for (int o = 32; o > 0; o >>= 1) v += __shfl_down(v, o);
    __shared__ float sred[2];
    if ((t & 63) == 0) sred[t >> 6] = v;
    __syncthreads();
    if (t == 0) out[0] = (sred[0] + sred[1]) * (1.f / 128.f) + 1e-5f;
}

extern "C" void kernel_launch(void* const* d_in, const int* in_sizes, int n_in,
                              void* d_out, int out_size, void* d_ws, size_t ws_size,
                              hipStream_t stream) {
    const float* X = (const float*)d_in[0];  // outputs (128,256,64) f32
    const float* Y = (const float*)d_in[1];  // targets (128,256,64) f32
    float* out = (float*)d_out;

    const size_t dbytes = (size_t)NPAIR * NSEQ * NSEQ * sizeof(unsigned short);
    const size_t need = dbytes + (size_t)NPAIR * sizeof(float);
    if (ws_size < need) {
        hipMemsetAsync(d_out, 0x7f, sizeof(float), stream);  // sentinel
        return;
    }
    unsigned short* Sws = (unsigned short*)d_ws;
    float* rws = (float*)((char*)d_ws + dbytes);

    dist_kernel<<<2 * NPAIR, 256, 0, stream>>>(X, Y, Sws);
    dtw_kernel<<<NPAIR, 64, 0, stream>>>(Sws, rws);
    reduce_kernel<<<1, 128, 0, stream>>>(rws, out);
}